// Round 22
// baseline (514.655 us; speedup 1.0000x reference)
//
#include <hip/hip_runtime.h>

#define M_DIM 16384
#define N_DIM 4096
#define K_DIM 4096
#define NCLUST 16

#define BM 128
#define BN 128
#define KB4 2048              // bytes per row (fp4: 4096 elements / 2)
#define TKB 64                // K-tile bytes per row (128 fp4 elements)
#define NT 32                 // K-tiles

typedef unsigned short u16;
typedef unsigned char u8;
typedef float floatx16 __attribute__((ext_vector_type(16)));
typedef int int4v __attribute__((ext_vector_type(4)));
typedef int int8v __attribute__((ext_vector_type(8)));

typedef const unsigned int __attribute__((address_space(1))) gu32;
typedef unsigned int __attribute__((address_space(3))) lu32;

// float -> fp4 e2m1 code (values pre-scaled to ~N(0,1)); grid {0,.5,1,1.5,2,3,4,6}
__device__ __forceinline__ unsigned f2fp4(float x) {
  unsigned s = (__float_as_uint(x) >> 28) & 0x8u;
  float ax = fabsf(x);
  unsigned m;
  if      (ax < 0.25f) m = 0;
  else if (ax < 0.75f) m = 1;
  else if (ax < 1.25f) m = 2;
  else if (ax < 1.75f) m = 3;
  else if (ax < 2.5f)  m = 4;
  else if (ax < 3.5f)  m = 5;
  else if (ax < 5.0f)  m = 6;
  else                 m = 7;
  return s | m;
}

// ---------------- zero colsq only (s_part is fully written each call) ----------------
__global__ __launch_bounds__(256) void zero_kernel(float* __restrict__ p, int n) {
  int i = blockIdx.x * 256 + threadIdx.x;
  if (i < n) p[i] = 0.f;
}

// ---------------- z row-normalize -> fp4 (x64) + copy z -> out1 (shared read) ----------------
__global__ __launch_bounds__(256) void znorm_copy_kernel(const float* __restrict__ z,
                                                         float* __restrict__ out1,
                                                         u8* __restrict__ zn) {
  const int row = blockIdx.x;
  const int t = threadIdx.x;
  const size_t base = (size_t)row * K_DIM;
  const float4* zr = (const float4*)(z + base);
  float4 v[4];                       // 16 contiguous elements: 16t .. 16t+15
  float ss = 0.f;
#pragma unroll
  for (int i = 0; i < 4; i++) {
    v[i] = zr[t * 4 + i];
    ss += v[i].x * v[i].x + v[i].y * v[i].y + v[i].z * v[i].z + v[i].w * v[i].w;
  }
#pragma unroll
  for (int m = 1; m <= 32; m <<= 1) ss += __shfl_xor(ss, m, 64);
  __shared__ float red[4];
  if ((t & 63) == 0) red[t >> 6] = ss;
  __syncthreads();
  float tot = red[0] + red[1] + red[2] + red[3];
  float sc = 64.0f / fmaxf(sqrtf(tot), 1e-8f);
  float4* o1 = (float4*)(out1 + base);
  uint2* znr = (uint2*)(zn + (size_t)row * KB4);
  unsigned wlo = 0, whi = 0;
#pragma unroll
  for (int i = 0; i < 4; i++) {
    o1[t * 4 + i] = v[i];
    unsigned p = f2fp4(v[i].x * sc) | (f2fp4(v[i].y * sc) << 4) |
                 (f2fp4(v[i].z * sc) << 8) | (f2fp4(v[i].w * sc) << 12);
    if (i < 2) wlo |= p << (16 * i); else whi |= p << (16 * (i - 2));
  }
  uint2 pk; pk.x = wlo; pk.y = whi;
  znr[t] = pk;
}

// ---------------- D column squared-norms ----------------
__global__ __launch_bounds__(256) void colsq_kernel(const float* __restrict__ D,
                                                    float* __restrict__ colsq) {
  const int col = blockIdx.x * 256 + threadIdx.x;
  const int r0 = blockIdx.y * 128;
  float ss = 0.f;
#pragma unroll 4
  for (int r = 0; r < 128; r++) {
    float d = D[(size_t)(r0 + r) * N_DIM + col];
    ss += d * d;
  }
  atomicAdd(&colsq[col], ss);
}

// ---------------- D col-normalize + transpose -> fp4 (x64) DnT[N][K/2] ----------------
__global__ __launch_bounds__(256) void dnt_kernel(const float* __restrict__ D,
                                                  const float* __restrict__ colsq,
                                                  u8* __restrict__ dnt) {
  __shared__ float tile[64][65];
  const int c0 = blockIdx.x * 64, r0 = blockIdx.y * 64;
  const int t = threadIdx.x;
  const int tr = t >> 4;
  const int tc = (t & 15) * 4;
#pragma unroll
  for (int i = 0; i < 4; i++) {
    int row = i * 16 + tr;
    float4 v = *(const float4*)(D + (size_t)(r0 + row) * N_DIM + c0 + tc);
    tile[row][tc + 0] = v.x; tile[row][tc + 1] = v.y;
    tile[row][tc + 2] = v.z; tile[row][tc + 3] = v.w;
  }
  __syncthreads();
#pragma unroll
  for (int i = 0; i < 4; i++) {
    int nl = i * 16 + tr;
    float sc = 64.0f / fmaxf(sqrtf(colsq[c0 + nl]), 1e-8f);
    u16 pk = (u16)(f2fp4(tile[tc + 0][nl] * sc) | (f2fp4(tile[tc + 1][nl] * sc) << 4) |
                   (f2fp4(tile[tc + 2][nl] * sc) << 8) | (f2fp4(tile[tc + 3][nl] * sc) << 12));
    *(u16*)(dnt + (size_t)(c0 + nl) * KB4 + ((r0 + tc) >> 1)) = pk;
  }
}

// ---------------- GEMM: 128x128, fp4, mfma_scale 32x32x64, 3 blocks/CU ----------------
// R22 = R21 geometry/pipeline with the MFMA shape swapped 16x16x128 ->
// 32x32x64 (µbench: +26% instruction throughput; half the instructions).
// Per wave: 64x64 out = 2x2 of 32x32, acc[2][2] x 16 = 64 AGPR (unchanged).
// Frag: row = l&31, k = (l>>5)*32 + i in v[0:3] (fp4 half-width). LDS chunk
// swizzle c' = c ^ (row&3) (c = kk*2 + hi) -> 2-way banks per 16-lane phase;
// staging source slot = (t&3) ^ ((t>>2)&3). kk-symmetric refill-in-shadow:
// 4 frags refilled after each 4-MFMA group. Epilogue uses the verified 32x32
// C/D map: col = l&31, row = (reg&3) + 8*(reg>>2) + 4*(l>>5).
__global__ __launch_bounds__(256, 3) void gemm_kernel(const u8* __restrict__ zn,
                                                      const u8* __restrict__ dnt,
                                                      float* __restrict__ s_part) {
  __shared__ u8 ldsA[3 * BM * TKB];   // 3 x 8 KB
  __shared__ u8 ldsB[3 * BN * TKB];   // 3 x 8 KB -> 48 KB total

  const int t = threadIdx.x;
  const int w = t >> 6, l = t & 63;
  const int hi = l >> 5;

  // XCD swizzle: 4096 blocks, 512 contiguous work-ids per XCD
  const int bid = blockIdx.x;
  const int swz = (bid & 7) * 512 + (bid >> 3);
  const int bx = swz & 31, by = swz >> 5;
  const int bm = by * BM, bn = bx * BN;
  const int wm = (w >> 1) * 64, wn = (w & 1) * 64;

  // ---- staging: pre-swizzled per-lane sources, wave-uniform LDS dests ----
  const int sslot = (t & 3) ^ ((t >> 2) & 3);
  const u8* pA = zn + (size_t)(bm + (t >> 2)) * KB4 + sslot * 16;
  const u8* pB = dnt + (size_t)(bn + (t >> 2)) * KB4 + sslot * 16;

#define STAGE(OA, KT) do { \
    __builtin_amdgcn_global_load_lds((gu32*)(pA + (KT) * TKB), \
        (lu32*)&ldsA[(OA) + w * 1024], 16, 0, 0); \
    __builtin_amdgcn_global_load_lds((gu32*)(pA + (size_t)64 * KB4 + (KT) * TKB), \
        (lu32*)&ldsA[(OA) + 4096 + w * 1024], 16, 0, 0); \
    __builtin_amdgcn_global_load_lds((gu32*)(pB + (KT) * TKB), \
        (lu32*)&ldsB[(OA) + w * 1024], 16, 0, 0); \
    __builtin_amdgcn_global_load_lds((gu32*)(pB + (size_t)64 * KB4 + (KT) * TKB), \
        (lu32*)&ldsB[(OA) + 4096 + w * 1024], 16, 0, 0); \
  } while (0)

  // ---- frag byte offsets: j = kk*2 + m(n); chunk c = kk*2 + hi, c' = c^(row&3)
  int aOff[4], bOff[4];
#pragma unroll
  for (int j = 0; j < 4; j++) {
    int kk = j >> 1, m = j & 1;
    int rowA = wm + m * 32 + (l & 31);
    aOff[j] = rowA * TKB + (((kk * 2 + hi) ^ (rowA & 3)) * 16);
    int rowB = wn + m * 32 + (l & 31);
    bOff[j] = rowB * TKB + (((kk * 2 + hi) ^ (rowB & 3)) * 16);
  }

  int8v af[4], bf[4];
  floatx16 acc[2][2] = {};

  // full-def refill: low half from LDS, high half zeroed (fp4 reads v[0:3])
#define LDFRAG(F, base, off) do { \
    int4v* _h = (int4v*)&(F); \
    _h[0] = *(const int4v*)((base) + (off)); \
    _h[1] = (int4v){0, 0, 0, 0}; \
  } while (0)

  // full-tile preload (prologue only)
#define READ_ALL(OA) do { \
    const u8* _ab = ldsA + (OA); \
    const u8* _bb = ldsB + (OA); \
    _Pragma("unroll") \
    for (int j = 0; j < 4; j++) { \
      LDFRAG(af[j], _ab, aOff[j]); \
      LDFRAG(bf[j], _bb, bOff[j]); \
    } \
  } while (0)

  // 4 MFMAs of one k-half: uses af[KK*2+m], bf[KK*2+n]
#define MFMA_G(KK) do { \
    __builtin_amdgcn_s_setprio(1); \
    _Pragma("unroll") \
    for (int mi = 0; mi < 2; mi++) \
      _Pragma("unroll") \
      for (int ni = 0; ni < 2; ni++) \
        acc[mi][ni] = __builtin_amdgcn_mfma_scale_f32_32x32x64_f8f6f4( \
            af[(KK) * 2 + mi], bf[(KK) * 2 + ni], acc[mi][ni], 4, 4, 0, 127u, 0, 127u); \
    __builtin_amdgcn_s_setprio(0); \
  } while (0)

#define VM4 asm volatile("s_waitcnt vmcnt(4)" ::: "memory")
#define VM0 asm volatile("s_waitcnt vmcnt(0)" ::: "memory")

  // one pipelined K-tile: all 8 frags of tile kt preloaded. ON = next buf.
#define ITER(OC, ON, STG, WT, RDNEXT) do { \
    __builtin_amdgcn_s_barrier(); \
    __builtin_amdgcn_sched_barrier(0); \
    STG; \
    MFMA_G(0); \
    WT; \
    if (RDNEXT) { \
      LDFRAG(af[0], ldsA + (ON), aOff[0]); \
      LDFRAG(af[1], ldsA + (ON), aOff[1]); \
      LDFRAG(bf[0], ldsB + (ON), bOff[0]); \
      LDFRAG(bf[1], ldsB + (ON), bOff[1]); \
    } \
    MFMA_G(1); \
    if (RDNEXT) { \
      LDFRAG(af[2], ldsA + (ON), aOff[2]); \
      LDFRAG(af[3], ldsA + (ON), aOff[3]); \
      LDFRAG(bf[2], ldsB + (ON), bOff[2]); \
      LDFRAG(bf[3], ldsB + (ON), bOff[3]); \
    } \
  } while (0)

#define O0 0
#define O1 8192
#define O2 16384

  // prologue: stage tiles 0,1; drain tile0 (keep tile1 flying); preload frags
  STAGE(O0, 0); STAGE(O1, 1);
  VM4;
  __builtin_amdgcn_s_barrier();
  READ_ALL(O0);

  for (int kt = 0; kt < NT - 2; kt += 3) {
    ITER(O0, O1, STAGE(O2, kt + 2), VM4, 1);
    ITER(O1, O2, STAGE(O0, kt + 3), VM4, 1);
    ITER(O2, O0, STAGE(O1, kt + 4), VM4, 1);
  }
  // kt = NT-2 (buf0): no stage; land tile NT-1; refill its frags
  ITER(O0, O1, ((void)0), VM0, 1);
  // kt = NT-1 (buf1): compute only
  ITER(O1, O1, ((void)0), ((void)0), 0);

#undef ITER
#undef READ_ALL
#undef O0
#undef O1
#undef O2
#undef VM4
#undef VM0
#undef MFMA_G
#undef LDFRAG
#undef STAGE

  // ---- epilogue: per-row square-sum over this wave's 64 cols (2 n-blocks),
  // 5-step shfl reduce within 32-lane halves, non-atomic s_part output.
  // C/D map: col = l&31, row_in_block = (reg&3) + 8*(reg>>2) + 4*hi.
  __syncthreads();
  float* red = (float*)ldsA;    // [128 rows][2 wave-cols]
#pragma unroll
  for (int m = 0; m < 2; m++) {
#pragma unroll
    for (int reg = 0; reg < 16; reg++) {
      float x0 = acc[m][0][reg], x1 = acc[m][1][reg];
      float s = x0 * x0 + x1 * x1;
      s += __shfl_xor(s, 1, 64);
      s += __shfl_xor(s, 2, 64);
      s += __shfl_xor(s, 4, 64);
      s += __shfl_xor(s, 8, 64);
      s += __shfl_xor(s, 16, 64);
      if ((l & 31) == 0) {
        int rib = (reg & 3) + 8 * (reg >> 2) + 4 * hi;
        red[(wm + m * 32 + rib) * 2 + (w & 1)] = s;
      }
    }
  }
  __syncthreads();
  if (t < 128) {
    float s = red[t * 2 + 0] + red[t * 2 + 1];
    // slot: [row][cluster][half] — exactly one writer per slot, no atomic
    s_part[((size_t)(bm + t) * NCLUST + (bx >> 1)) * 2 + (bx & 1)] = s;
  }
}

// ---------------- softmax over 16 clusters per row (sums the 2 partials) ----------------
__global__ __launch_bounds__(256) void softmax_kernel(const float* __restrict__ s_part,
                                                      float* __restrict__ out0) {
  int r = blockIdx.x * 256 + threadIdx.x;
  const float4* sp = (const float4*)(s_part + (size_t)r * 32);
  float v[16];
#pragma unroll
  for (int i = 0; i < 8; i++) {
    float4 a = sp[i];
    v[i * 2 + 0] = a.x + a.y;
    v[i * 2 + 1] = a.z + a.w;
  }
  // logits = (s_scaled / 2^24) / TEMP ; eta*d cancels in softmax
  const float lsc = 5.9604644775390625e-7f;   // 10 / 2^24
  float mx = -1e30f;
#pragma unroll
  for (int i = 0; i < 16; i++) { v[i] *= lsc; mx = fmaxf(mx, v[i]); }
  float sum = 0.f;
#pragma unroll
  for (int i = 0; i < 16; i++) { v[i] = __expf(v[i] - mx); sum += v[i]; }
  float rs = 1.0f / sum;
  float4* op = (float4*)(out0 + (size_t)r * 16);
#pragma unroll
  for (int i = 0; i < 4; i++) {
    float4 a;
    a.x = v[i * 4 + 0] * rs; a.y = v[i * 4 + 1] * rs;
    a.z = v[i * 4 + 2] * rs; a.w = v[i * 4 + 3] * rs;
    op[i] = a;
  }
}

extern "C" void kernel_launch(void* const* d_in, const int* in_sizes, int n_in,
                              void* d_out, int out_size, void* d_ws, size_t ws_size,
                              hipStream_t stream) {
  const float* z = (const float*)d_in[0];
  const float* D = (const float*)d_in[1];
  float* out0 = (float*)d_out;
  float* out1 = out0 + (size_t)M_DIM * NCLUST;

  char* ws = (char*)d_ws;
  u8* zn   = (u8*)ws;                                                 // 32 MB
  u8* dnt  = (u8*)(ws + (size_t)M_DIM * KB4);                         // 8 MB
  float* colsq  = (float*)(ws + (size_t)M_DIM * KB4 + (size_t)N_DIM * KB4);
  float* s_part = colsq + N_DIM;                                      // [M][16][2] = 2 MB

  zero_kernel<<<(N_DIM + 255) / 256, 256, 0, stream>>>(colsq, N_DIM);
  znorm_copy_kernel<<<M_DIM, 256, 0, stream>>>(z, out1, zn);
  colsq_kernel<<<dim3(N_DIM / 256, N_DIM / 128), 256, 0, stream>>>(D, colsq);
  dnt_kernel<<<dim3(N_DIM / 64, N_DIM / 64), 256, 0, stream>>>(D, colsq, dnt);
  gemm_kernel<<<(M_DIM / BM) * (N_DIM / BN), 256, 0, stream>>>(zn, dnt, s_part);
  softmax_kernel<<<M_DIM / 256, 256, 0, stream>>>(s_part, out0);
}

// Round 23
// 341.413 us; speedup vs baseline: 1.5074x; 1.5074x over previous
//
#include <hip/hip_runtime.h>

#define M_DIM 16384
#define N_DIM 4096
#define K_DIM 4096
#define NCLUST 16

#define BM 128
#define BN 128
#define KB4 2048              // bytes per row (fp4: 4096 elements / 2)
#define TKB 64                // K-tile bytes per row (128 fp4 elements)
#define NT 32                 // K-tiles

typedef unsigned short u16;
typedef unsigned char u8;
typedef float floatx4 __attribute__((ext_vector_type(4)));
typedef int int4v __attribute__((ext_vector_type(4)));
typedef int int8v __attribute__((ext_vector_type(8)));

typedef const unsigned int __attribute__((address_space(1))) gu32;
typedef unsigned int __attribute__((address_space(3))) lu32;

// float -> fp4 e2m1 code (values pre-scaled to ~N(0,1)); grid {0,.5,1,1.5,2,3,4,6}
__device__ __forceinline__ unsigned f2fp4(float x) {
  unsigned s = (__float_as_uint(x) >> 28) & 0x8u;
  float ax = fabsf(x);
  unsigned m;
  if      (ax < 0.25f) m = 0;
  else if (ax < 0.75f) m = 1;
  else if (ax < 1.25f) m = 2;
  else if (ax < 1.75f) m = 3;
  else if (ax < 2.5f)  m = 4;
  else if (ax < 3.5f)  m = 5;
  else if (ax < 5.0f)  m = 6;
  else                 m = 7;
  return s | m;
}

// ---------------- zero colsq only (s_part is fully written each call) ----------------
__global__ __launch_bounds__(256) void zero_kernel(float* __restrict__ p, int n) {
  int i = blockIdx.x * 256 + threadIdx.x;
  if (i < n) p[i] = 0.f;
}

// ---------------- z row-normalize -> fp4 (x64) + copy z -> out1 (shared read) ----------------
__global__ __launch_bounds__(256) void znorm_copy_kernel(const float* __restrict__ z,
                                                         float* __restrict__ out1,
                                                         u8* __restrict__ zn) {
  const int row = blockIdx.x;
  const int t = threadIdx.x;
  const size_t base = (size_t)row * K_DIM;
  const float4* zr = (const float4*)(z + base);
  float4 v[4];                       // 16 contiguous elements: 16t .. 16t+15
  float ss = 0.f;
#pragma unroll
  for (int i = 0; i < 4; i++) {
    v[i] = zr[t * 4 + i];
    ss += v[i].x * v[i].x + v[i].y * v[i].y + v[i].z * v[i].z + v[i].w * v[i].w;
  }
#pragma unroll
  for (int m = 1; m <= 32; m <<= 1) ss += __shfl_xor(ss, m, 64);
  __shared__ float red[4];
  if ((t & 63) == 0) red[t >> 6] = ss;
  __syncthreads();
  float tot = red[0] + red[1] + red[2] + red[3];
  float sc = 64.0f / fmaxf(sqrtf(tot), 1e-8f);
  float4* o1 = (float4*)(out1 + base);
  uint2* znr = (uint2*)(zn + (size_t)row * KB4);
  unsigned wlo = 0, whi = 0;
#pragma unroll
  for (int i = 0; i < 4; i++) {
    o1[t * 4 + i] = v[i];
    unsigned p = f2fp4(v[i].x * sc) | (f2fp4(v[i].y * sc) << 4) |
                 (f2fp4(v[i].z * sc) << 8) | (f2fp4(v[i].w * sc) << 12);
    if (i < 2) wlo |= p << (16 * i); else whi |= p << (16 * (i - 2));
  }
  uint2 pk; pk.x = wlo; pk.y = whi;
  znr[t] = pk;
}

// ---------------- D column squared-norms ----------------
__global__ __launch_bounds__(256) void colsq_kernel(const float* __restrict__ D,
                                                    float* __restrict__ colsq) {
  const int col = blockIdx.x * 256 + threadIdx.x;
  const int r0 = blockIdx.y * 128;
  float ss = 0.f;
#pragma unroll 4
  for (int r = 0; r < 128; r++) {
    float d = D[(size_t)(r0 + r) * N_DIM + col];
    ss += d * d;
  }
  atomicAdd(&colsq[col], ss);
}

// ---------------- D col-normalize + transpose -> fp4 (x64) DnT[N][K/2] ----------------
__global__ __launch_bounds__(256) void dnt_kernel(const float* __restrict__ D,
                                                  const float* __restrict__ colsq,
                                                  u8* __restrict__ dnt) {
  __shared__ float tile[64][65];
  const int c0 = blockIdx.x * 64, r0 = blockIdx.y * 64;
  const int t = threadIdx.x;
  const int tr = t >> 4;
  const int tc = (t & 15) * 4;
#pragma unroll
  for (int i = 0; i < 4; i++) {
    int row = i * 16 + tr;
    float4 v = *(const float4*)(D + (size_t)(r0 + row) * N_DIM + c0 + tc);
    tile[row][tc + 0] = v.x; tile[row][tc + 1] = v.y;
    tile[row][tc + 2] = v.z; tile[row][tc + 3] = v.w;
  }
  __syncthreads();
#pragma unroll
  for (int i = 0; i < 4; i++) {
    int nl = i * 16 + tr;
    float sc = 64.0f / fmaxf(sqrtf(colsq[c0 + nl]), 1e-8f);
    u16 pk = (u16)(f2fp4(tile[tc + 0][nl] * sc) | (f2fp4(tile[tc + 1][nl] * sc) << 4) |
                   (f2fp4(tile[tc + 2][nl] * sc) << 8) | (f2fp4(tile[tc + 3][nl] * sc) << 12));
    *(u16*)(dnt + (size_t)(c0 + nl) * KB4 + ((r0 + tc) >> 1)) = pk;
  }
}

// ---------------- GEMM: 128x128 tile, 4 waves, 3 blocks/CU, fp4 16x16x128 ----------------
// R23 = R21 verbatim (best verified: GEMM 179 µs, 0 conflicts, no spill).
// Structure: 64x64/wave via 16x16x128 mfma_scale (unit scales), depth-2
// 3-buffer pipeline, refill-in-MFMA-shadow, slot swizzle lk^((row>>1)&3)
// on both sides, 3 blocks/CU cross-block overlap, non-atomic s_part.
__global__ __launch_bounds__(256, 3) void gemm_kernel(const u8* __restrict__ zn,
                                                      const u8* __restrict__ dnt,
                                                      float* __restrict__ s_part) {
  __shared__ u8 ldsA[3 * BM * TKB];   // 3 x 8 KB
  __shared__ u8 ldsB[3 * BN * TKB];   // 3 x 8 KB -> 48 KB total

  const int t = threadIdx.x;
  const int w = t >> 6, l = t & 63;
  const int lr = l & 15, lk = l >> 4;

  // XCD swizzle: 4096 blocks, 512 contiguous work-ids per XCD
  const int bid = blockIdx.x;
  const int swz = (bid & 7) * 512 + (bid >> 3);
  const int bx = swz & 31, by = swz >> 5;
  const int bm = by * BM, bn = bx * BN;
  const int wm = (w >> 1) * 64, wn = (w & 1) * 64;

  // ---- staging: pre-swizzled per-lane sources, wave-uniform LDS dests ----
  const int sslot = (t & 3) ^ ((t >> 3) & 3);
  const u8* pA = zn + (size_t)(bm + (t >> 2)) * KB4 + sslot * 16;
  const u8* pB = dnt + (size_t)(bn + (t >> 2)) * KB4 + sslot * 16;

#define STAGE(OA, KT) do { \
    __builtin_amdgcn_global_load_lds((gu32*)(pA + (KT) * TKB), \
        (lu32*)&ldsA[(OA) + w * 1024], 16, 0, 0); \
    __builtin_amdgcn_global_load_lds((gu32*)(pA + (size_t)64 * KB4 + (KT) * TKB), \
        (lu32*)&ldsA[(OA) + 4096 + w * 1024], 16, 0, 0); \
    __builtin_amdgcn_global_load_lds((gu32*)(pB + (KT) * TKB), \
        (lu32*)&ldsB[(OA) + w * 1024], 16, 0, 0); \
    __builtin_amdgcn_global_load_lds((gu32*)(pB + (size_t)64 * KB4 + (KT) * TKB), \
        (lu32*)&ldsB[(OA) + 4096 + w * 1024], 16, 0, 0); \
  } while (0)

  // ---- ds_read fragment byte offsets: slot = lk ^ ((row>>1)&3) ----
  int aOff[4], bOff[4];
#pragma unroll
  for (int m = 0; m < 4; m++) {
    int row = wm + m * 16 + lr;
    aOff[m] = row * TKB + ((lk ^ ((row >> 1) & 3)) * 16);
  }
#pragma unroll
  for (int n = 0; n < 4; n++) {
    int row = wn + n * 16 + lr;
    bOff[n] = row * TKB + ((lk ^ ((row >> 1) & 3)) * 16);
  }

  int8v af[4], bf[4];
  floatx4 acc[4][4] = {};

  // full-def refill: low half from LDS, high half zeroed (fp4 reads v[0:3])
#define LDFRAG(F, base, off) do { \
    int4v* _h = (int4v*)&(F); \
    _h[0] = *(const int4v*)((base) + (off)); \
    _h[1] = (int4v){0, 0, 0, 0}; \
  } while (0)

  // full-tile preload (prologue only)
#define READ_ALL(OA) do { \
    const u8* _ab = ldsA + (OA); \
    const u8* _bb = ldsB + (OA); \
    _Pragma("unroll") \
    for (int ni = 0; ni < 4; ni++) LDFRAG(bf[ni], _bb, bOff[ni]); \
    _Pragma("unroll") \
    for (int mi = 0; mi < 4; mi++) LDFRAG(af[mi], _ab, aOff[mi]); \
  } while (0)

#define MFMA_H(M0) do { \
    __builtin_amdgcn_s_setprio(1); \
    _Pragma("unroll") \
    for (int mi = 0; mi < 2; mi++) \
      _Pragma("unroll") \
      for (int ni = 0; ni < 4; ni++) \
        acc[(M0) + mi][ni] = __builtin_amdgcn_mfma_scale_f32_16x16x128_f8f6f4( \
            af[(M0) + mi], bf[ni], acc[(M0) + mi][ni], 4, 4, 0, 127u, 0, 127u); \
    __builtin_amdgcn_s_setprio(0); \
  } while (0)

#define VM4 asm volatile("s_waitcnt vmcnt(4)" ::: "memory")
#define VM0 asm volatile("s_waitcnt vmcnt(0)" ::: "memory")

  // one pipelined K-tile: all 8 frags of tile kt preloaded. ON = next buf.
#define ITER(OC, ON, STG, WT, RDNEXT) do { \
    __builtin_amdgcn_s_barrier(); \
    __builtin_amdgcn_sched_barrier(0); \
    STG; \
    MFMA_H(0); \
    WT; \
    if (RDNEXT) { \
      LDFRAG(af[0], ldsA + (ON), aOff[0]); \
      LDFRAG(af[1], ldsA + (ON), aOff[1]); \
    } \
    MFMA_H(2); \
    if (RDNEXT) { \
      const u8* _bb = ldsB + (ON); \
      _Pragma("unroll") \
      for (int ni = 0; ni < 4; ni++) LDFRAG(bf[ni], _bb, bOff[ni]); \
      LDFRAG(af[2], ldsA + (ON), aOff[2]); \
      LDFRAG(af[3], ldsA + (ON), aOff[3]); \
    } \
  } while (0)

#define O0 0
#define O1 8192
#define O2 16384

  // prologue: stage tiles 0,1; drain tile0 (keep tile1 flying); preload frags
  STAGE(O0, 0); STAGE(O1, 1);
  VM4;
  __builtin_amdgcn_s_barrier();
  READ_ALL(O0);

  for (int kt = 0; kt < NT - 2; kt += 3) {
    ITER(O0, O1, STAGE(O2, kt + 2), VM4, 1);
    ITER(O1, O2, STAGE(O0, kt + 3), VM4, 1);
    ITER(O2, O0, STAGE(O1, kt + 4), VM4, 1);
  }
  // kt = NT-2 (buf0): no stage; land tile NT-1; refill its frags
  ITER(O0, O1, ((void)0), VM0, 1);
  // kt = NT-1 (buf1): compute only
  ITER(O1, O1, ((void)0), ((void)0), 0);

#undef ITER
#undef READ_ALL
#undef O0
#undef O1
#undef O2
#undef VM4
#undef VM0
#undef MFMA_H
#undef LDFRAG
#undef STAGE

  // ---- epilogue: per-row square-sum over this wave's 64 cols; 2 N-halves
  // reduce via LDS; ONE non-atomic store per row into this block's slot.
  __syncthreads();
  float* red = (float*)ldsA;    // [128 rows][2 wave-cols]
#pragma unroll
  for (int m = 0; m < 4; m++) {
#pragma unroll
    for (int r = 0; r < 4; r++) {
      float v = 0.f;
#pragma unroll
      for (int n = 0; n < 4; n++) { float x = acc[m][n][r]; v += x * x; }
      v += __shfl_xor(v, 1, 64);
      v += __shfl_xor(v, 2, 64);
      v += __shfl_xor(v, 4, 64);
      v += __shfl_xor(v, 8, 64);
      if (lr == 0) {
        int lrow = wm + m * 16 + lk * 4 + r;   // 0..127
        red[lrow * 2 + (w & 1)] = v;
      }
    }
  }
  __syncthreads();
  if (t < 128) {
    float s = red[t * 2 + 0] + red[t * 2 + 1];
    // slot: [row][cluster][half] — exactly one writer per slot, no atomic
    s_part[((size_t)(bm + t) * NCLUST + (bx >> 1)) * 2 + (bx & 1)] = s;
  }
}

// ---------------- softmax over 16 clusters per row (sums the 2 partials) ----------------
__global__ __launch_bounds__(256) void softmax_kernel(const float* __restrict__ s_part,
                                                      float* __restrict__ out0) {
  int r = blockIdx.x * 256 + threadIdx.x;
  const float4* sp = (const float4*)(s_part + (size_t)r * 32);
  float v[16];
#pragma unroll
  for (int i = 0; i < 8; i++) {
    float4 a = sp[i];
    v[i * 2 + 0] = a.x + a.y;
    v[i * 2 + 1] = a.z + a.w;
  }
  // logits = (s_scaled / 2^24) / TEMP ; eta*d cancels in softmax
  const float lsc = 5.9604644775390625e-7f;   // 10 / 2^24
  float mx = -1e30f;
#pragma unroll
  for (int i = 0; i < 16; i++) { v[i] *= lsc; mx = fmaxf(mx, v[i]); }
  float sum = 0.f;
#pragma unroll
  for (int i = 0; i < 16; i++) { v[i] = __expf(v[i] - mx); sum += v[i]; }
  float rs = 1.0f / sum;
  float4* op = (float4*)(out0 + (size_t)r * 16);
#pragma unroll
  for (int i = 0; i < 4; i++) {
    float4 a;
    a.x = v[i * 4 + 0] * rs; a.y = v[i * 4 + 1] * rs;
    a.z = v[i * 4 + 2] * rs; a.w = v[i * 4 + 3] * rs;
    op[i] = a;
  }
}

extern "C" void kernel_launch(void* const* d_in, const int* in_sizes, int n_in,
                              void* d_out, int out_size, void* d_ws, size_t ws_size,
                              hipStream_t stream) {
  const float* z = (const float*)d_in[0];
  const float* D = (const float*)d_in[1];
  float* out0 = (float*)d_out;
  float* out1 = out0 + (size_t)M_DIM * NCLUST;

  char* ws = (char*)d_ws;
  u8* zn   = (u8*)ws;                                                 // 32 MB
  u8* dnt  = (u8*)(ws + (size_t)M_DIM * KB4);                         // 8 MB
  float* colsq  = (float*)(ws + (size_t)M_DIM * KB4 + (size_t)N_DIM * KB4);
  float* s_part = colsq + N_DIM;                                      // [M][16][2] = 2 MB

  zero_kernel<<<(N_DIM + 255) / 256, 256, 0, stream>>>(colsq, N_DIM);
  znorm_copy_kernel<<<M_DIM, 256, 0, stream>>>(z, out1, zn);
  colsq_kernel<<<dim3(N_DIM / 256, N_DIM / 128), 256, 0, stream>>>(D, colsq);
  dnt_kernel<<<dim3(N_DIM / 64, N_DIM / 64), 256, 0, stream>>>(D, colsq, dnt);
  gemm_kernel<<<(M_DIM / BM) * (N_DIM / BN), 256, 0, stream>>>(zn, dnt, s_part);
  softmax_kernel<<<M_DIM / 256, 256, 0, stream>>>(s_part, out0);
}